// Round 1
// 386.989 us; speedup vs baseline: 1.1979x; 1.1979x over previous
//
#include <hip/hip_runtime.h>
#include <math.h>

#define B_ 16
#define S_ 1024
#define D_ 512
#define H_ 4
#define INV_TEMP 0.044194173824159216f   // 1/sqrt(512)
#define C_SCALE 0.00390625f              // 2^-8: keeps head-4 scores inside fp16 range
#define OUT_SCALE 256.0f

typedef _Float16 f16;
typedef _Float16 f16x8 __attribute__((ext_vector_type(8)));
typedef _Float16 f16x4 __attribute__((ext_vector_type(4)));
typedef float f32x4 __attribute__((ext_vector_type(4)));

#define AS1(p) ((const __attribute__((address_space(1))) void*)(p))
#define AS3(p) ((__attribute__((address_space(3))) void*)(p))
#define MFMA __builtin_amdgcn_mfma_f32_16x16x32_f16

// ---------------------------------------------------------------------------
// fp32 -> fp16 convert
// ---------------------------------------------------------------------------
__global__ __launch_bounds__(256)
void k_conv(const float* __restrict__ src, f16* __restrict__ dst)
{
    const int i = blockIdx.x * 256 + threadIdx.x;
    const float4 v = ((const float4*)src)[i];
    f16x4 h; h[0] = (f16)v.x; h[1] = (f16)v.y; h[2] = (f16)v.z; h[3] = (f16)v.w;
    ((f16x4*)dst)[i] = h;
}

// ---------------------------------------------------------------------------
// pad flags: flag[b*8+kt] = 1 iff any event_type[b, kt*128 .. kt*128+127] == 0
// (head-invariant; computed once). Lower-triangular score tiles with no pad
// key are EXACTLY zero and can be skipped everywhere.
// ---------------------------------------------------------------------------
__global__ __launch_bounds__(128)
void k_flags(const int* __restrict__ etype, int* __restrict__ flag)
{
    const int t = threadIdx.x;           // 128 = B_ * 8
    const int b = t >> 3, kt = t & 7;
    const int* p = etype + b * S_ + kt * 128;
    int any0 = 0;
#pragma unroll
    for (int i = 0; i < 128; i += 4) {
        const int4 v = *(const int4*)(p + i);
        any0 |= (v.x == 0) | (v.y == 0) | (v.z == 0) | (v.w == 0);
    }
    flag[t] = any0;
}

// ---------------------------------------------------------------------------
// m97-style staging/MMA core (proven round 2)
// ---------------------------------------------------------------------------
__device__ __forceinline__ void stage128x32(const f16* __restrict__ src, int ld,
                                            char* lds0, int t)
{
    const f16* g0 = src + (size_t)(t >> 2) * ld + (t & 3) * 8;
    __builtin_amdgcn_global_load_lds(AS1(g0), AS3(lds0 + t * 16), 16, 0, 0);
    const f16* g1 = g0 + (size_t)64 * ld;
    __builtin_amdgcn_global_load_lds(AS1(g1), AS3(lds0 + 4096 + t * 16), 16, 0, 0);
}

__device__ __forceinline__ void mma_chunk(const char* ldsA, const char* ldsB,
                                          int wm, int wn, int lr, int quad,
                                          f32x4 (*acc)[4])
{
    f16x8 af[4], bf[4];
#pragma unroll
    for (int i = 0; i < 4; ++i)
        af[i] = *(const f16x8*)(ldsA + ((wm * 64 + i * 16 + lr) * 32 + quad * 8) * 2);
#pragma unroll
    for (int j = 0; j < 4; ++j)
        bf[j] = *(const f16x8*)(ldsB + ((wn * 64 + j * 16 + lr) * 32 + quad * 8) * 2);
#pragma unroll
    for (int i = 0; i < 4; ++i)
#pragma unroll
        for (int j = 0; j < 4; ++j)
            acc[i][j] = MFMA(af[i], bf[j], acc[i][j], 0, 0, 0);
}

__device__ __forceinline__ void gemm_core(const f16* A, int ldA, const f16* Bm, int ldB,
                                          int K, char* lds, int t, int wm, int wn,
                                          int lr, int quad, f32x4 (*acc)[4])
{
    for (int k0 = 0; k0 < K; k0 += 32) {
        stage128x32(A + k0, ldA, lds, t);
        stage128x32(Bm + k0, ldB, lds + 8192, t);
        __syncthreads();
        mma_chunk(lds, lds + 8192, wm, wn, lr, quad, acc);
        __syncthreads();
    }
}

// ===========================================================================
// Merged per-head producer kernel. Both halves depend only on xh:
//   blocks [0,1024): scores  (long pole first; ~44% early-exit on mask skip)
//   blocks [1024,1536): vT = ELU(x @ W^T + b)^T stored [B][D][S] fp16
// 1024 and 1536 are multiples of 8, so the XCD-pinned mappings of both
// original kernels survive the merge unchanged.
// ===========================================================================
__global__ __launch_bounds__(256)
void k_vs(const f16* __restrict__ xh, const f16* __restrict__ Wh,
          const float* __restrict__ bias, f16* __restrict__ vT,
          const int* __restrict__ etype, const int* __restrict__ flag,
          f16* __restrict__ sh)
{
    __shared__ __align__(16) char lds[16384];
    const int t = threadIdx.x;
    const int w = t >> 6, lane = t & 63, lr = lane & 15, quad = lane >> 4;
    const int wm = w & 1, wn = w >> 1;

    if (blockIdx.x < 1024) {
        // ---------------- scores ----------------
        const int i0 = blockIdx.x;
        const int xcd = i0 & 7, j0 = i0 >> 3;          // j0 in [0,128)
        const int b = 2 * xcd + (j0 & 1);
        const int tile = j0 >> 1;                      // [0,64)
        const int bk = (tile & 7) * 128;               // keys (M)
        const int bq = (tile >> 3) * 128;              // queries (N)
        // fully-masked tile: every k <= every q and no pad key -> exact zero.
        // Never computed, never written; sh was zeroed once up front.
        if (bk < bq && !flag[b * 8 + (bk >> 7)]) return;

        const f16* xb = xh + (size_t)b * S_ * D_;
        f32x4 acc[4][4] = {};
        gemm_core(xb + (size_t)bk * D_, D_, xb + (size_t)bq * D_, D_, D_,
                  lds, t, wm, wn, lr, quad, acc);
        const float sc = INV_TEMP * C_SCALE;
#pragma unroll
        for (int i = 0; i < 4; ++i) {
            const int k4 = bk + wm * 64 + i * 16 + quad * 4;
            const int4 et = *(const int4*)(etype + b * S_ + k4);
            const int ev[4] = {et.x, et.y, et.z, et.w};
#pragma unroll
            for (int j = 0; j < 4; ++j) {
                const int q = bq + wn * 64 + j * 16 + lr;
                f16x4 hv;
#pragma unroll
                for (int r = 0; r < 4; ++r) {
                    const bool keep = ((k4 + r) > q) || (ev[r] == 0);
                    hv[r] = (f16)(keep ? acc[i][j][r] * sc : 0.0f);
                }
                *(f16x4*)(sh + ((size_t)b * S_ + q) * S_ + k4) = hv;
            }
        }
    } else {
        // ---------------- vT = ELU(x @ W^T + b)^T ----------------
        const int idx = blockIdx.x - 1024;
        const int bm = (idx & 127) * 128;              // rows of x (B*S)
        const int bn = (idx >> 7) * 128;               // output features e
        f32x4 acc[4][4] = {};
        gemm_core(xh + (size_t)bm * D_, D_, Wh + (size_t)bn * D_, D_, D_,
                  lds, t, wm, wn, lr, quad, acc);
#pragma unroll
        for (int j = 0; j < 4; ++j) {
            const int e = bn + wn * 64 + j * 16 + lr;
            const float be = bias[e];
#pragma unroll
            for (int i = 0; i < 4; ++i) {
                const int m = bm + wm * 64 + i * 16 + quad * 4;
                const int batch = m >> 10, s = m & 1023;
                f16x4 hv;
#pragma unroll
                for (int r = 0; r < 4; ++r) {
                    float z = acc[i][j][r] + be;
                    z = (z > 0.0f) ? z : (expf(z) - 1.0f);
                    hv[r] = (f16)z;
                }
                *(f16x4*)(vT + ((size_t)batch * D_ + e) * S_ + s) = hv;
            }
        }
    }
}

// ===========================================================================
// k_rownorm (unchanged math): 4096 blocks, 4 rows/block (1/wave).
// Skipped score tiles read as exact zeros (sh zero-filled once up front).
// ===========================================================================
__global__ __launch_bounds__(256)
void k_rownorm(const f16* __restrict__ sh, float* __restrict__ inv)
{
    const int w = threadIdx.x >> 6, lane = threadIdx.x & 63;
    const int i0 = blockIdx.x;
    const int xcd = i0 & 7, j0 = i0 >> 3;          // j0 in [0,512)
    const int b = 2 * xcd + (j0 & 1);
    const int row = b * S_ + (j0 >> 1) * 4 + w;
    const f16* p = sh + (size_t)row * S_;
    const f16x8 a = *(const f16x8*)(p + lane * 8);
    const f16x8 c = *(const f16x8*)(p + 512 + lane * 8);
    float ss = 0.0f;
#pragma unroll
    for (int r = 0; r < 8; ++r) {
        const float x = (float)a[r]; ss += x * x;
        const float y = (float)c[r]; ss += y * y;
    }
#pragma unroll
    for (int off = 32; off; off >>= 1) ss += __shfl_down(ss, off, 64);
    if (lane == 0) {
        const float norm_true = sqrtf(ss) * OUT_SCALE;   // undo C_SCALE
        inv[row] = 1.0f / (C_SCALE * fmaxf(norm_true, 1e-5f));
    }
}

// ===========================================================================
// k_out: 512 blocks, XCD-pinned. K-loop now walks 8 key-tiles of 128 and
// skips tiles that are exact zero (k <= q everywhere, no pad key).
// Average kept: ~60% of the K range.
// ===========================================================================
__global__ __launch_bounds__(256)
void k_out(const f16* __restrict__ vT, const f16* __restrict__ sh,
           const float* __restrict__ inv, const int* __restrict__ flag,
           f16* __restrict__ xh, float* __restrict__ out, const int accum)
{
    __shared__ __align__(16) char lds[16384];
    const int t = threadIdx.x;
    const int w = t >> 6, lane = t & 63, lr = lane & 15, quad = lane >> 4;
    const int wm = w & 1, wn = w >> 1;
    const int i0 = blockIdx.x;
    const int xcd = i0 & 7, j0 = i0 >> 3;          // j0 in [0,64)
    const int b = 2 * xcd + (j0 & 1);
    const int tile = j0 >> 1;                      // [0,32)
    const int be = (tile & 3) * 128;               // e (M), fastest
    const int bq = (tile >> 2) * 128;              // q (N)
    const int qt = bq >> 7;

    const f16* Abase = vT + ((size_t)b * D_ + be) * S_;
    const f16* Bbase = sh + ((size_t)b * S_ + bq) * S_;
    f32x4 acc[4][4] = {};
#pragma unroll 1
    for (int kt = 0; kt < 8; ++kt) {
        if (kt < qt && !flag[b * 8 + kt]) continue;   // block-uniform skip
        const int kb = kt * 128;
        for (int k0 = kb; k0 < kb + 128; k0 += 32) {
            stage128x32(Abase + k0, S_, lds, t);
            stage128x32(Bbase + k0, S_, lds + 8192, t);
            __syncthreads();
            mma_chunk(lds, lds + 8192, wm, wn, lr, quad, acc);
            __syncthreads();
        }
    }
#pragma unroll
    for (int j = 0; j < 4; ++j) {
        const int q = bq + wn * 64 + j * 16 + lr;
        const float scl = inv[b * S_ + q];
#pragma unroll
        for (int i = 0; i < 4; ++i) {
            const int e4 = be + wm * 64 + i * 16 + quad * 4;
            const size_t o = ((size_t)b * S_ + q) * D_ + e4;
            f32x4 xnew;
            f16x4 hx;
#pragma unroll
            for (int r = 0; r < 4; ++r) {
                xnew[r] = acc[i][j][r] * scl;
                hx[r] = (f16)xnew[r];
            }
            f32x4 val = xnew;
            if (accum) { const f32x4 old = *(const f32x4*)(out + o); val = val + old; }
            *(f32x4*)(out + o) = val;
            *(f16x4*)(xh + o) = hx;
        }
    }
}

// ---------------------------------------------------------------------------
// Workspace: xh @0 (16M), vT @16M (16M), sh @32M (32M), Wh @64M (2M),
//            inv @66M (64K), flags @66M+64K (512B)
// ---------------------------------------------------------------------------
extern "C" void kernel_launch(void* const* d_in, const int* in_sizes, int n_in,
                              void* d_out, int out_size, void* d_ws, size_t ws_size,
                              hipStream_t stream) {
    const float* x0    = (const float*)d_in[0];
    const int*   etype = (const int*)d_in[2];
    const float* W     = (const float*)d_in[3];
    const float* bias  = (const float*)d_in[4];
    float* out = (float*)d_out;

    char* ws = (char*)d_ws;
    f16*   xh    = (f16*)(ws);
    f16*   vT    = (f16*)(ws + (16u << 20));
    f16*   sh    = (f16*)(ws + (32u << 20));
    f16*   Wh    = (f16*)(ws + (64u << 20));
    float* inv   = (float*)(ws + (66u << 20));
    int*   flags = (int*)(ws + (66u << 20) + 65536);

    k_conv <<<8192, 256, 0, stream>>>(x0, xh);
    k_conv <<<1024, 256, 0, stream>>>(W, Wh);
    k_flags<<<1, 128, 0, stream>>>(etype, flags);
    // zero sh once: skipped (never-written) tiles must read as exact zeros
    // for rownorm; the skip set is head-invariant so one memset suffices.
    hipMemsetAsync(sh, 0, (size_t)32 << 20, stream);

    for (int h = 0; h < H_; ++h) {
        k_vs     <<<1536, 256, 0, stream>>>(xh, Wh + (size_t)h * D_ * D_,
                                            bias + (size_t)h * D_, vT,
                                            etype, flags, sh);
        k_rownorm<<<4096, 256, 0, stream>>>(sh, inv);
        k_out    <<<512, 256, 0, stream>>>(vT, sh, inv, flags, xh, out, h > 0);
    }
}

// Round 2
// 371.571 us; speedup vs baseline: 1.2477x; 1.0415x over previous
//
#include <hip/hip_runtime.h>
#include <math.h>

#define B_ 16
#define S_ 1024
#define D_ 512
#define H_ 4
#define INV_TEMP 0.044194173824159216f   // 1/sqrt(512)
#define C_SCALE 0.00390625f              // 2^-8: keeps head-4 scores inside fp16 range
#define OUT_SCALE 256.0f

typedef _Float16 f16;
typedef _Float16 f16x8 __attribute__((ext_vector_type(8)));
typedef _Float16 f16x4 __attribute__((ext_vector_type(4)));
typedef float f32x4 __attribute__((ext_vector_type(4)));

#define AS1(p) ((const __attribute__((address_space(1))) void*)(p))
#define AS3(p) ((__attribute__((address_space(3))) void*)(p))
#define MFMA __builtin_amdgcn_mfma_f32_16x16x32_f16

// ---------------------------------------------------------------------------
// fp32 -> fp16 convert
// ---------------------------------------------------------------------------
__global__ __launch_bounds__(256)
void k_conv(const float* __restrict__ src, f16* __restrict__ dst)
{
    const int i = blockIdx.x * 256 + threadIdx.x;
    const float4 v = ((const float4*)src)[i];
    f16x4 h; h[0] = (f16)v.x; h[1] = (f16)v.y; h[2] = (f16)v.z; h[3] = (f16)v.w;
    ((f16x4*)dst)[i] = h;
}

// ---------------------------------------------------------------------------
// pad flags: flag[b*8+kt] = 1 iff any event_type[b, kt*128 .. kt*128+127] == 0
// (head-invariant; computed once). Lower-triangular score tiles with no pad
// key are EXACTLY zero and can be skipped everywhere.
// ---------------------------------------------------------------------------
__global__ __launch_bounds__(128)
void k_flags(const int* __restrict__ etype, int* __restrict__ flag)
{
    const int t = threadIdx.x;           // 128 = B_ * 8
    const int b = t >> 3, kt = t & 7;
    const int* p = etype + b * S_ + kt * 128;
    int any0 = 0;
#pragma unroll
    for (int i = 0; i < 128; i += 4) {
        const int4 v = *(const int4*)(p + i);
        any0 |= (v.x == 0) | (v.y == 0) | (v.z == 0) | (v.w == 0);
    }
    flag[t] = any0;
}

// ---------------------------------------------------------------------------
// m97-style staging/MMA core (proven round 2)
// ---------------------------------------------------------------------------
__device__ __forceinline__ void stage128x32(const f16* __restrict__ src, int ld,
                                            char* lds0, int t)
{
    const f16* g0 = src + (size_t)(t >> 2) * ld + (t & 3) * 8;
    __builtin_amdgcn_global_load_lds(AS1(g0), AS3(lds0 + t * 16), 16, 0, 0);
    const f16* g1 = g0 + (size_t)64 * ld;
    __builtin_amdgcn_global_load_lds(AS1(g1), AS3(lds0 + 4096 + t * 16), 16, 0, 0);
}

__device__ __forceinline__ void mma_chunk(const char* ldsA, const char* ldsB,
                                          int wm, int wn, int lr, int quad,
                                          f32x4 (*acc)[4])
{
    f16x8 af[4], bf[4];
#pragma unroll
    for (int i = 0; i < 4; ++i)
        af[i] = *(const f16x8*)(ldsA + ((wm * 64 + i * 16 + lr) * 32 + quad * 8) * 2);
#pragma unroll
    for (int j = 0; j < 4; ++j)
        bf[j] = *(const f16x8*)(ldsB + ((wn * 64 + j * 16 + lr) * 32 + quad * 8) * 2);
#pragma unroll
    for (int i = 0; i < 4; ++i)
#pragma unroll
        for (int j = 0; j < 4; ++j)
            acc[i][j] = MFMA(af[i], bf[j], acc[i][j], 0, 0, 0);
}

__device__ __forceinline__ void gemm_core(const f16* A, int ldA, const f16* Bm, int ldB,
                                          int K, char* lds, int t, int wm, int wn,
                                          int lr, int quad, f32x4 (*acc)[4])
{
    for (int k0 = 0; k0 < K; k0 += 32) {
        stage128x32(A + k0, ldA, lds, t);
        stage128x32(Bm + k0, ldB, lds + 8192, t);
        __syncthreads();
        mma_chunk(lds, lds + 8192, wm, wn, lr, quad, acc);
        __syncthreads();
    }
}

// ===========================================================================
// Merged per-head producer kernel. Both halves depend only on xh:
//   blocks [0,1024): scores  (long pole first; ~44% early-exit on mask skip)
//                    + fused row-norm partial: Sum(s^2) per q-row via atomics
//   blocks [1024,1536): vT = ELU(x @ W^T + b)^T stored [B][D][S] fp16
// ===========================================================================
__global__ __launch_bounds__(256)
void k_vs(const f16* __restrict__ xh, const f16* __restrict__ Wh,
          const float* __restrict__ bias, f16* __restrict__ vT,
          const int* __restrict__ etype, const int* __restrict__ flag,
          f16* __restrict__ sh, float* __restrict__ ss)
{
    __shared__ __align__(16) char lds[16384];
    const int t = threadIdx.x;
    const int w = t >> 6, lane = t & 63, lr = lane & 15, quad = lane >> 4;
    const int wm = w & 1, wn = w >> 1;

    if (blockIdx.x < 1024) {
        // ---------------- scores ----------------
        const int i0 = blockIdx.x;
        const int xcd = i0 & 7, j0 = i0 >> 3;          // j0 in [0,128)
        const int b = 2 * xcd + (j0 & 1);
        const int tile = j0 >> 1;                      // [0,64)
        const int bk = (tile & 7) * 128;               // keys (M)
        const int bq = (tile >> 3) * 128;              // queries (N)
        // fully-masked tile: every k <= every q and no pad key -> exact zero.
        // Never computed, never written; sh was zeroed once up front, and the
        // ss contribution is exactly 0.
        if (bk < bq && !flag[b * 8 + (bk >> 7)]) return;

        const f16* xb = xh + (size_t)b * S_ * D_;
        f32x4 acc[4][4] = {};
        gemm_core(xb + (size_t)bk * D_, D_, xb + (size_t)bq * D_, D_, D_,
                  lds, t, wm, wn, lr, quad, acc);
        const float sc = INV_TEMP * C_SCALE;
        float ssq[4] = {0.0f, 0.0f, 0.0f, 0.0f};
#pragma unroll
        for (int i = 0; i < 4; ++i) {
            const int k4 = bk + wm * 64 + i * 16 + quad * 4;
            const int4 et = *(const int4*)(etype + b * S_ + k4);
            const int ev[4] = {et.x, et.y, et.z, et.w};
#pragma unroll
            for (int j = 0; j < 4; ++j) {
                const int q = bq + wn * 64 + j * 16 + lr;
                f16x4 hv;
#pragma unroll
                for (int r = 0; r < 4; ++r) {
                    const bool keep = ((k4 + r) > q) || (ev[r] == 0);
                    hv[r] = (f16)(keep ? acc[i][j][r] * sc : 0.0f);
                    const float fv = (float)hv[r];
                    ssq[j] += fv * fv;               // matches rownorm: sum of
                }                                    // squares of STORED fp16
                *(f16x4*)(sh + ((size_t)b * S_ + q) * S_ + k4) = hv;
            }
        }
        // reduce Sum(s^2) over the 4 quads (same q lives in lanes lr, lr^16,
        // lr^32, lr^48), then one float atomic per (q, wave).
#pragma unroll
        for (int j = 0; j < 4; ++j) {
            float v = ssq[j];
            v += __shfl_xor(v, 16, 64);
            v += __shfl_xor(v, 32, 64);
            if (quad == 0) {
                const int q = bq + wn * 64 + j * 16 + lr;
                atomicAdd(ss + b * S_ + q, v);
            }
        }
    } else {
        // ---------------- vT = ELU(x @ W^T + b)^T ----------------
        const int idx = blockIdx.x - 1024;
        const int bm = (idx & 127) * 128;              // rows of x (B*S)
        const int bn = (idx >> 7) * 128;               // output features e
        f32x4 acc[4][4] = {};
        gemm_core(xh + (size_t)bm * D_, D_, Wh + (size_t)bn * D_, D_, D_,
                  lds, t, wm, wn, lr, quad, acc);
#pragma unroll
        for (int j = 0; j < 4; ++j) {
            const int e = bn + wn * 64 + j * 16 + lr;
            const float be = bias[e];
#pragma unroll
            for (int i = 0; i < 4; ++i) {
                const int m = bm + wm * 64 + i * 16 + quad * 4;
                const int batch = m >> 10, s = m & 1023;
                f16x4 hv;
#pragma unroll
                for (int r = 0; r < 4; ++r) {
                    float z = acc[i][j][r] + be;
                    z = (z > 0.0f) ? z : (expf(z) - 1.0f);
                    hv[r] = (f16)z;
                }
                *(f16x4*)(vT + ((size_t)batch * D_ + e) * S_ + s) = hv;
            }
        }
    }
}

// ===========================================================================
// k_out: 512 blocks, XCD-pinned. K-loop walks 8 key-tiles of 128 and skips
// tiles that are exact zero (k <= q everywhere, no pad key). The row-norm
// reciprocal is computed inline from the fused Sum(s^2) accumulator.
// ===========================================================================
__global__ __launch_bounds__(256)
void k_out(const f16* __restrict__ vT, const f16* __restrict__ sh,
           const float* __restrict__ ss, const int* __restrict__ flag,
           f16* __restrict__ xh, float* __restrict__ out, const int accum)
{
    __shared__ __align__(16) char lds[16384];
    const int t = threadIdx.x;
    const int w = t >> 6, lane = t & 63, lr = lane & 15, quad = lane >> 4;
    const int wm = w & 1, wn = w >> 1;
    const int i0 = blockIdx.x;
    const int xcd = i0 & 7, j0 = i0 >> 3;          // j0 in [0,64)
    const int b = 2 * xcd + (j0 & 1);
    const int tile = j0 >> 1;                      // [0,32)
    const int be = (tile & 3) * 128;               // e (M), fastest
    const int bq = (tile >> 2) * 128;              // q (N)
    const int qt = bq >> 7;

    const f16* Abase = vT + ((size_t)b * D_ + be) * S_;
    const f16* Bbase = sh + ((size_t)b * S_ + bq) * S_;
    f32x4 acc[4][4] = {};
#pragma unroll 1
    for (int kt = 0; kt < 8; ++kt) {
        if (kt < qt && !flag[b * 8 + kt]) continue;   // block-uniform skip
        const int kb = kt * 128;
        for (int k0 = kb; k0 < kb + 128; k0 += 32) {
            stage128x32(Abase + k0, S_, lds, t);
            stage128x32(Bbase + k0, S_, lds + 8192, t);
            __syncthreads();
            mma_chunk(lds, lds + 8192, wm, wn, lr, quad, acc);
            __syncthreads();
        }
    }
#pragma unroll
    for (int j = 0; j < 4; ++j) {
        const int q = bq + wn * 64 + j * 16 + lr;
        // inv = 1 / (C * max(sqrt(ss)*OUT_SCALE, eps))  -- same math as the
        // old k_rownorm, ss accumulated by k_vs from the stored fp16 scores.
        const float ssv = ss[b * S_ + q];
        const float scl = 1.0f / (C_SCALE * fmaxf(sqrtf(ssv) * OUT_SCALE, 1e-5f));
#pragma unroll
        for (int i = 0; i < 4; ++i) {
            const int e4 = be + wm * 64 + i * 16 + quad * 4;
            const size_t o = ((size_t)b * S_ + q) * D_ + e4;
            f32x4 xnew;
            f16x4 hx;
#pragma unroll
            for (int r = 0; r < 4; ++r) {
                xnew[r] = acc[i][j][r] * scl;
                hx[r] = (f16)xnew[r];
            }
            f32x4 val = xnew;
            if (accum) { const f32x4 old = *(const f32x4*)(out + o); val = val + old; }
            *(f32x4*)(out + o) = val;
            *(f16x4*)(xh + o) = hx;
        }
    }
}

// ---------------------------------------------------------------------------
// Workspace: xh @0 (16M), vT @16M (16M), sh @32M (32M), Wh @64M (2M),
//            ss  @66M (4 heads x 64K = 256K), flags @66M+256K (512B)
// ---------------------------------------------------------------------------
extern "C" void kernel_launch(void* const* d_in, const int* in_sizes, int n_in,
                              void* d_out, int out_size, void* d_ws, size_t ws_size,
                              hipStream_t stream) {
    const float* x0    = (const float*)d_in[0];
    const int*   etype = (const int*)d_in[2];
    const float* W     = (const float*)d_in[3];
    const float* bias  = (const float*)d_in[4];
    float* out = (float*)d_out;

    char* ws = (char*)d_ws;
    f16*   xh    = (f16*)(ws);
    f16*   vT    = (f16*)(ws + (16u << 20));
    f16*   sh    = (f16*)(ws + (32u << 20));
    f16*   Wh    = (f16*)(ws + (64u << 20));
    float* ssb   = (float*)(ws + (66u << 20));
    int*   flags = (int*)(ws + (66u << 20) + 262144);

    k_conv <<<8192, 256, 0, stream>>>(x0, xh);
    k_conv <<<1024, 256, 0, stream>>>(W, Wh);
    k_flags<<<1, 128, 0, stream>>>(etype, flags);
    // zero sh once: skipped (never-written) tiles must read as exact zeros;
    // the skip set is head-invariant so one memset covers all 4 heads.
    hipMemsetAsync(sh, 0, (size_t)32 << 20, stream);
    // zero all 4 per-head Sum(s^2) accumulators once.
    hipMemsetAsync(ssb, 0, 4 * (size_t)B_ * S_ * sizeof(float), stream);

    for (int h = 0; h < H_; ++h) {
        float* ss = ssb + (size_t)h * B_ * S_;
        k_vs <<<1536, 256, 0, stream>>>(xh, Wh + (size_t)h * D_ * D_,
                                        bias + (size_t)h * D_, vT,
                                        etype, flags, sh, ss);
        k_out<<<512, 256, 0, stream>>>(vT, sh, ss, flags, xh, out, h > 0);
    }
}